// Round 10
// baseline (132.035 us; speedup 1.0000x reference)
//
#include <hip/hip_runtime.h>

#define N_ELEMS_C 400000
#define N_NODES_C 200000
#define STATE_N   3200000                      // N_ELEMS * NQ * 1
#define N_BLOCKS  ((N_ELEMS_C + 511) / 512)    // 782 (2 elems/thread)

#define WS_PARTIALS_OFF 0   // d_ws: [0, 4*N_BLOCKS) per-block partials

typedef float v4f __attribute__((ext_vector_type(4)));
typedef int   v4i __attribute__((ext_vector_type(4)));

// R10: 2 kernels (repack dropped — R3/R8 showed direct 4B-aligned dwordx4
// gather from the 12-B us records is equivalent). Energy kernel processes
// TWO elements per thread: doubles per-wave memory-level parallelism (16
// gathers + 8 stream loads in flight), halves vmcnt-wait events per unit
// work, and amortizes the LDS shape-grad reads over both elements. Barrier
// placed BEFORE any VMEM so there is no mid-kernel vmcnt(0) drain.
__global__ __launch_bounds__(256) void fused_energy_kernel(
    const float* __restrict__ params,
    const float* __restrict__ us,          // [N_NODES][3]
    const float* __restrict__ shape_grads, // [8][8][3] = [q][n][d]
    const float* __restrict__ jxws,        // [E][8]
    const int*   __restrict__ conns,       // [E][8]
    const float* __restrict__ state_old,   // [E*8]
    float* __restrict__ partials,          // [N_BLOCKS]
    float* __restrict__ out)               // [1 + E*8]
{
    __shared__ __align__(16) float s_sgT[192];  // [q][d][n] transposed
    __shared__ float s_wsum[4];
    const int tid = threadIdx.x;
    const int b   = blockIdx.x;

    if (tid < 192) {
        const int q = tid / 24;
        const int r = tid % 24;
        const int d = r / 8;
        const int n = r % 8;
        s_sgT[tid] = shape_grads[(q * 8 + n) * 3 + d];
    }
    __syncthreads();   // nothing in flight yet: cheap barrier, no vmcnt drain

    const int e0 = b * 512 + tid;
    const int e1 = e0 + 256;
    const bool a0 = (e0 < N_ELEMS_C), a1 = (e1 < N_ELEMS_C);

    // ---- issue all independent long-latency loads, max MLP ----
    v4i c00={0,0,0,0}, c01={0,0,0,0}, c10={0,0,0,0}, c11={0,0,0,0};
    v4f j00={0,0,0,0}, j01={0,0,0,0}, j10={0,0,0,0}, j11={0,0,0,0};
    const v4i* cp = reinterpret_cast<const v4i*>(conns);
    const v4f* jp = reinterpret_cast<const v4f*>(jxws);
    if (a0) {
        c00 = __builtin_nontemporal_load(cp + 2 * e0 + 0);
        c01 = __builtin_nontemporal_load(cp + 2 * e0 + 1);
        j00 = __builtin_nontemporal_load(jp + 2 * e0 + 0);
        j01 = __builtin_nontemporal_load(jp + 2 * e0 + 1);
    }
    if (a1) {
        c10 = __builtin_nontemporal_load(cp + 2 * e1 + 0);
        c11 = __builtin_nontemporal_load(cp + 2 * e1 + 1);
        j10 = __builtin_nontemporal_load(jp + 2 * e1 + 0);
        j11 = __builtin_nontemporal_load(jp + 2 * e1 + 1);
    }

    // state passthrough: 4 float4 per thread
    const int base4 = b * 1024;
    v4f sv[4];
    bool ok[4];
    #pragma unroll
    for (int k = 0; k < 4; ++k) {
        const int i4 = base4 + k * 256 + tid;
        ok[k] = (i4 < STATE_N / 4);
        if (ok[k]) sv[k] = __builtin_nontemporal_load(
                       reinterpret_cast<const v4f*>(state_old) + i4);
    }

    // ---- 16 gathers issue as soon as conns lands (4B-aligned dwordx4) ----
    v4f uv0[8], uv1[8];
    if (a0) {
        const int ci[8] = {c00.x, c00.y, c00.z, c00.w, c01.x, c01.y, c01.z, c01.w};
        #pragma unroll
        for (int n = 0; n < 8; ++n)
            uv0[n] = *reinterpret_cast<const v4f*>(us + 3 * (size_t)ci[n]);
    }
    if (a1) {
        const int ci[8] = {c10.x, c10.y, c10.z, c10.w, c11.x, c11.y, c11.z, c11.w};
        #pragma unroll
        for (int n = 0; n < 8; ++n)
            uv1[n] = *reinterpret_cast<const v4f*>(us + 3 * (size_t)ci[n]);
    }

    // ---- state stores overlap the in-flight gathers ----
    #pragma unroll
    for (int k = 0; k < 4; ++k) {
        if (ok[k]) {
            const int i = (base4 + k * 256 + tid) * 4;
            __builtin_nontemporal_store(sv[k].x, out + 1 + i + 0);
            __builtin_nontemporal_store(sv[k].y, out + 1 + i + 1);
            __builtin_nontemporal_store(sv[k].z, out + 1 + i + 2);
            __builtin_nontemporal_store(sv[k].w, out + 1 + i + 3);
        }
    }

    const float mu  = params[0];
    const float lam = params[1];
    const float jq0[8] = {j00.x, j00.y, j00.z, j00.w, j01.x, j01.y, j01.z, j01.w};
    const float jq1[8] = {j10.x, j10.y, j10.z, j10.w, j11.x, j11.y, j11.z, j11.w};

    float acc = 0.0f;
    #pragma unroll
    for (int q = 0; q < 8; ++q) {
        // one set of LDS b128 reads serves BOTH elements
        const v4f* sgq = reinterpret_cast<const v4f*>(s_sgT + q * 24);
        const v4f A0 = sgq[0], A1 = sgq[1];   // d=0, n=0..7
        const v4f B0 = sgq[2], B1 = sgq[3];   // d=1
        const v4f C0 = sgq[4], C1 = sgq[5];   // d=2
        const float d0[8] = {A0.x, A0.y, A0.z, A0.w, A1.x, A1.y, A1.z, A1.w};
        const float d1[8] = {B0.x, B0.y, B0.z, B0.w, B1.x, B1.y, B1.z, B1.w};
        const float d2[8] = {C0.x, C0.y, C0.z, C0.w, C1.x, C1.y, C1.z, C1.w};

        #pragma unroll
        for (int el = 0; el < 2; ++el) {
            const bool act = el ? a1 : a0;
            if (!act) continue;
            const v4f* uv = el ? uv1 : uv0;
            const float jw = el ? jq1[q] : jq0[q];

            float g00=0.f,g01=0.f,g02=0.f,g10=0.f,g11=0.f,g12=0.f,g20=0.f,g21=0.f,g22=0.f;
            #pragma unroll
            for (int n = 0; n < 8; ++n) {
                const float u0 = uv[n].x, u1 = uv[n].y, u2 = uv[n].z;
                g00 = fmaf(d0[n], u0, g00); g01 = fmaf(d1[n], u0, g01); g02 = fmaf(d2[n], u0, g02);
                g10 = fmaf(d0[n], u1, g10); g11 = fmaf(d1[n], u1, g11); g12 = fmaf(d2[n], u1, g12);
                g20 = fmaf(d0[n], u2, g20); g21 = fmaf(d1[n], u2, g21); g22 = fmaf(d2[n], u2, g22);
            }
            const float F00 = g00 + 1.0f, F01 = g01,        F02 = g02;
            const float F10 = g10,        F11 = g11 + 1.0f, F12 = g12;
            const float F20 = g20,        F21 = g21,        F22 = g22 + 1.0f;

            const float det = F00 * (F11 * F22 - F12 * F21)
                            - F01 * (F10 * F22 - F12 * F20)
                            + F02 * (F10 * F21 - F11 * F20);
            const float I1 = F00*F00 + F01*F01 + F02*F02
                           + F10*F10 + F11*F11 + F12*F12
                           + F20*F20 + F21*F21 + F22*F22;
            const float lj = __logf(det);
            const float fq = 0.5f * mu * (I1 - 3.0f - 2.0f * lj)
                           + 0.5f * lam * lj * lj;
            acc = fmaf(jw, fq, acc);
        }
    }

    // wave-64 shuffle reduce -> per-block LDS reduce -> one store per block
    #pragma unroll
    for (int off = 32; off > 0; off >>= 1)
        acc += __shfl_down(acc, off, 64);
    const int lane = tid & 63;
    const int wv   = tid >> 6;
    if (lane == 0) s_wsum[wv] = acc;
    __syncthreads();
    if (tid == 0) {
        partials[b] = s_wsum[0] + s_wsum[1] + s_wsum[2] + s_wsum[3];
    }
}

// Kernel 2: reduce the 782 per-block partials; single block, writes out[0].
__global__ __launch_bounds__(256) void final_reduce_kernel(
    const float* __restrict__ partials, float* __restrict__ out)
{
    __shared__ float s_wsum[4];
    const int tid = threadIdx.x;
    float acc = 0.0f;
    for (int i = tid; i < N_BLOCKS; i += 256) acc += partials[i];
    #pragma unroll
    for (int off = 32; off > 0; off >>= 1)
        acc += __shfl_down(acc, off, 64);
    const int lane = tid & 63;
    const int wv   = tid >> 6;
    if (lane == 0) s_wsum[wv] = acc;
    __syncthreads();
    if (tid == 0) {
        out[0] = s_wsum[0] + s_wsum[1] + s_wsum[2] + s_wsum[3];
    }
}

extern "C" void kernel_launch(void* const* d_in, const int* in_sizes, int n_in,
                              void* d_out, int out_size, void* d_ws, size_t ws_size,
                              hipStream_t stream) {
    const float* params      = (const float*)d_in[0];
    // d_in[1] coords, d_in[2] t, d_in[4] shape_vals, d_in[7] dt — dead inputs
    const float* us          = (const float*)d_in[3];
    const float* shape_grads = (const float*)d_in[5];
    const float* jxws        = (const float*)d_in[6];
    const float* state_old   = (const float*)d_in[8];
    const int*   conns       = (const int*)d_in[9];
    float* out      = (float*)d_out;
    float* partials = (float*)((char*)d_ws + WS_PARTIALS_OFF);

    hipLaunchKernelGGL(fused_energy_kernel,
                       dim3(N_BLOCKS), dim3(256), 0, stream,
                       params, us, shape_grads, jxws, conns, state_old,
                       partials, out);
    hipLaunchKernelGGL(final_reduce_kernel,
                       dim3(1), dim3(256), 0, stream,
                       partials, out);
}